// Round 6
// baseline (353.772 us; speedup 1.0000x reference)
//
#include <hip/hip_runtime.h>
#include <hip/hip_bf16.h>
#include <stdint.h>

#define N_TOK 2048
#define HID   2048
#define NEXP  8
#define DFF   1408

typedef __attribute__((ext_vector_type(8))) short short8;
typedef __attribute__((ext_vector_type(4))) float f32x4;

__device__ __forceinline__ unsigned short f2bf(float f) {
  union { float ff; uint32_t u; } v; v.ff = f;
  return (unsigned short)((v.u + 0x7FFFu + ((v.u >> 16) & 1u)) >> 16);
}

__device__ __forceinline__ void gl2lds16(const void* g, void* l) {
  __builtin_amdgcn_global_load_lds(
      (const __attribute__((address_space(1))) void*)g,
      (__attribute__((address_space(3))) void*)l, 16, 0, 0);
}

// ---------------- K1: gating ----------------
__global__ __launch_bounds__(256) void gate_topk_k(
    const float* __restrict__ h, const float* __restrict__ gw,
    int* __restrict__ cnt, int* __restrict__ topk_idx, float* __restrict__ topk_w)
{
  int token = blockIdx.x * 4 + (threadIdx.x >> 6);
  int lane  = threadIdx.x & 63;
  const float* hr = h + (size_t)token * HID;
  float acc[NEXP];
#pragma unroll
  for (int e = 0; e < NEXP; ++e) acc[e] = 0.f;
  for (int i = lane; i < HID; i += 64) {
    float hv = hr[i];
#pragma unroll
    for (int e = 0; e < NEXP; ++e) acc[e] = fmaf(hv, gw[e * HID + i], acc[e]);
  }
#pragma unroll
  for (int e = 0; e < NEXP; ++e) {
    float a = acc[e];
#pragma unroll
    for (int s = 32; s > 0; s >>= 1) a += __shfl_xor(a, s, 64);
    acc[e] = a;
  }
  if (lane == 0) {
    float m = acc[0];
#pragma unroll
    for (int e = 1; e < NEXP; ++e) m = fmaxf(m, acc[e]);
    float w[NEXP]; float s = 0.f;
#pragma unroll
    for (int e = 0; e < NEXP; ++e) { w[e] = __expf(acc[e] - m); s += w[e]; }
    float inv = 1.f / s;
    int i0 = 0; float b0 = acc[0];
#pragma unroll
    for (int e = 1; e < NEXP; ++e) if (acc[e] > b0) { b0 = acc[e]; i0 = e; }
    int i1 = -1; float b1 = -3.4e38f;
#pragma unroll
    for (int e = 0; e < NEXP; ++e) if (e != i0 && acc[e] > b1) { b1 = acc[e]; i1 = e; }
    topk_idx[token * 2 + 0] = i0;
    topk_idx[token * 2 + 1] = i1;
    topk_w[token * 2 + 0] = w[i0] * inv;
    topk_w[token * 2 + 1] = w[i1] * inv;
    atomicAdd(&cnt[i0], 1);
    atomicAdd(&cnt[i1], 1);
  }
}

// ---------------- K2: prefix ----------------
__global__ void prefix_k(const int* __restrict__ cnt, int* __restrict__ offs,
                         int* __restrict__ cursor) {
  if (threadIdx.x == 0 && blockIdx.x == 0) {
    int s = 0;
    for (int e = 0; e < NEXP; ++e) { offs[e] = s; cursor[e] = s; s += cnt[e]; }
  }
}

// ---------------- K3: scatter (+ inverse map tok_slot) ----------------
__global__ __launch_bounds__(256) void scatter_k(
    const int* __restrict__ topk_idx, const float* __restrict__ topk_w,
    int* __restrict__ cursor, int* __restrict__ pair_token, float* __restrict__ pair_w,
    int* __restrict__ tok_slot)
{
  int n = blockIdx.x * 256 + threadIdx.x;
  if (n >= N_TOK) return;
#pragma unroll
  for (int k = 0; k < 2; ++k) {
    int e = topk_idx[n * 2 + k];
    int p = atomicAdd(&cursor[e], 1);
    pair_token[p] = n;
    pair_w[p] = topk_w[n * 2 + k];
    tok_slot[n * 2 + k] = p;
  }
}

// ---------------- K4: h fp32 -> bf16 ----------------
__global__ __launch_bounds__(256) void convert_h_k(const float* __restrict__ src,
                                                   unsigned short* __restrict__ dst) {
  int i = blockIdx.x * 256 + threadIdx.x;
  float4 a = ((const float4*)src)[(size_t)i * 2];
  float4 b = ((const float4*)src)[(size_t)i * 2 + 1];
  unsigned short o[8] = {f2bf(a.x), f2bf(a.y), f2bf(a.z), f2bf(a.w),
                         f2bf(b.x), f2bf(b.y), f2bf(b.z), f2bf(b.w)};
  *(short8*)&dst[(size_t)i * 8] = *(const short8*)o;
}

// ---------------- K5: fragment-pack  src fp32 [z][R][C] -> bf16 B-frag chunks ------
// chunk(fb = f/16, kb = k/32): 64 lanes x 16B; lane l=(fq<<4)|fr holds
// src[kb*32 + fq*8 + j][fb*16 + fr], j=0..7.  offset = (fb*(R/32)+kb)*512 + l*8.
__global__ __launch_bounds__(256) void fragpack_k(const float* __restrict__ s1,
                                                  unsigned short* __restrict__ d1,
                                                  const float* __restrict__ s2,
                                                  unsigned short* __restrict__ d2,
                                                  int R, int C, int nz1)
{
  __shared__ unsigned short T[64 * 66];
  const size_t sl = (size_t)R * C;
  int z = blockIdx.z;
  const float* s; unsigned short* d;
  if (z < nz1) { s = s1 + (size_t)z * sl; d = d1 + (size_t)z * sl; }
  else { s = s2 + (size_t)(z - nz1) * sl; d = d2 + (size_t)(z - nz1) * sl; }
  const int rb = blockIdx.x * 64, cb = blockIdx.y * 64;
  const int t = threadIdx.x;
  const int tr = t >> 4, tc = (t & 15) * 4;
  const float* sp = s + (size_t)(rb + tr) * C + cb + tc;
#pragma unroll
  for (int i = 0; i < 4; ++i) {
    float4 v = *(const float4*)(sp + (size_t)i * 16 * C);
    int r = tr + i * 16;
    uint32_t p0 = (uint32_t)f2bf(v.x) | ((uint32_t)f2bf(v.y) << 16);
    uint32_t p1 = (uint32_t)f2bf(v.z) | ((uint32_t)f2bf(v.w) << 16);
    *(uint32_t*)&T[r * 66 + tc]     = p0;
    *(uint32_t*)&T[r * 66 + tc + 2] = p1;
  }
  __syncthreads();
  const int KB = R >> 5;
#pragma unroll
  for (int sI = 0; sI < 2; ++sI) {
    int idx = t + sI * 256;
    int l2 = idx & 63, kbl = (idx >> 6) & 1, fbl = idx >> 7;
    int fr2 = l2 & 15, fq2 = l2 >> 4;
    unsigned short buf[8];
#pragma unroll
    for (int j = 0; j < 8; ++j)
      buf[j] = T[(kbl * 32 + fq2 * 8 + j) * 66 + fbl * 16 + fr2];
    int fbG = blockIdx.y * 4 + fbl;
    int kbG = blockIdx.x * 2 + kbl;
    *(short8*)(d + ((size_t)(fbG * KB + kbG) * 512 + l2 * 8)) = *(const short8*)buf;
  }
}

// ---------------- K6: grouped GEMM gate+up (tile 128x64, 4 waves) -----------------
// A: LDS dbuf (tok-gathered gl2lds, src-swizzled). B: fragment-packed global -> regs,
// 2-deep static rotation. Counted vmcnt(12) = 4 A-gl2lds + 8 B-loads per K-step.
__global__ __launch_bounds__(256) void gateup6_k(
    const unsigned short* __restrict__ hbf,
    const unsigned short* __restrict__ wgp, const unsigned short* __restrict__ wup,
    const int* __restrict__ cnt, const int* __restrict__ offs,
    const int* __restrict__ pair_token, unsigned short* __restrict__ act,
    int e_fixed, int nw, int nbcnt, size_t wstride)
{
  const int x = blockIdx.x;
  const int wti = x % nw, mb = x / nw;
  int e, nb;
  if (e_fixed >= 0) { e = e_fixed; nb = wti; }
  else { e = wti / nbcnt; nb = wti % nbcnt; }
  const int count = cnt[e];
  if (mb * 128 >= count) return;
  const int off = offs[e];
  const int rows = min(128, count - mb * 128);
  const int c0 = nb * 64;

  __shared__ unsigned short As[2][128 * 64];
  __shared__ int tok[128];

  const int t = threadIdx.x;
  if (t < 128) tok[t] = pair_token[off + mb * 128 + min(t, rows - 1)];
  __syncthreads();

  const int w = t >> 6, l = t & 63;
  const int rbase = w * 8 + (l >> 3);
  const int sc = ((l & 7) ^ (l >> 3)) * 8;

  const unsigned short* aP[4];
#pragma unroll
  for (int i = 0; i < 4; ++i)
    aP[i] = hbf + (size_t)tok[i * 32 + rbase] * HID + sc;

  const size_t wb = (e_fixed >= 0) ? 0 : (size_t)e * wstride;
  const int fr = l & 15, fq = l >> 4;
  const int wr = (w >> 1) * 64, wc = (w & 1) * 32;
  const unsigned short* bgB[2];
  const unsigned short* buB[2];
#pragma unroll
  for (int ni = 0; ni < 2; ++ni) {
    int fb = (c0 + wc) / 16 + ni;
    bgB[ni] = wgp + wb + (size_t)fb * (HID / 32) * 512 + l * 8;
    buB[ni] = wup + wb + (size_t)fb * (HID / 32) * 512 + l * 8;
  }

  f32x4 accg[4][2], accu[4][2];
#pragma unroll
  for (int i = 0; i < 4; ++i)
#pragma unroll
    for (int j = 0; j < 2; ++j) {
      accg[i][j] = (f32x4){0.f, 0.f, 0.f, 0.f};
      accu[i][j] = (f32x4){0.f, 0.f, 0.f, 0.f};
    }

  auto stage = [&](int b, int k) {
#pragma unroll
    for (int i = 0; i < 4; ++i)
      gl2lds16(aP[i] + k * 64, &As[b][(i * 32 + w * 8) * 64]);
  };
  auto loadB = [&](short8 (&bg)[2][2], short8 (&bu)[2][2], int k) {
#pragma unroll
    for (int kk = 0; kk < 2; ++kk)
#pragma unroll
      for (int ni = 0; ni < 2; ++ni) {
        bg[ni][kk] = *(const short8*)(bgB[ni] + (size_t)(k * 2 + kk) * 512);
        bu[ni][kk] = *(const short8*)(buB[ni] + (size_t)(k * 2 + kk) * 512);
      }
  };
  auto compute = [&](int b, short8 (&bg)[2][2], short8 (&bu)[2][2]) {
    short8 af[4][2];
#pragma unroll
    for (int kk = 0; kk < 2; ++kk) {
      const int ch = ((kk * 4 + fq) ^ (fr & 7)) * 8;
#pragma unroll
      for (int mi = 0; mi < 4; ++mi)
        af[mi][kk] = *(const short8*)&As[b][(wr + mi * 16 + fr) * 64 + ch];
    }
    __builtin_amdgcn_s_setprio(1);
#pragma unroll
    for (int kk = 0; kk < 2; ++kk)
#pragma unroll
      for (int mi = 0; mi < 4; ++mi)
#pragma unroll
        for (int ni = 0; ni < 2; ++ni) {
          accg[mi][ni] = __builtin_amdgcn_mfma_f32_16x16x32_bf16(af[mi][kk], bg[ni][kk], accg[mi][ni], 0, 0, 0);
          accu[mi][ni] = __builtin_amdgcn_mfma_f32_16x16x32_bf16(af[mi][kk], bu[ni][kk], accu[mi][ni], 0, 0, 0);
        }
    __builtin_amdgcn_s_setprio(0);
  };

  short8 g0[2][2], u0[2][2], g1[2][2], u1[2][2];
  const int NK = HID / 64;   // 32 (even)
  stage(0, 0); loadB(g0, u0, 0);
  for (int k = 0; k + 2 < NK; k += 2) {
    stage(1, k + 1); loadB(g1, u1, k + 1);
    asm volatile("s_waitcnt vmcnt(12)" ::: "memory");
    asm volatile("s_barrier" ::: "memory");
    compute(0, g0, u0);
    asm volatile("s_barrier" ::: "memory");
    stage(0, k + 2); loadB(g0, u0, k + 2);
    asm volatile("s_waitcnt vmcnt(12)" ::: "memory");
    asm volatile("s_barrier" ::: "memory");
    compute(1, g1, u1);
    asm volatile("s_barrier" ::: "memory");
  }
  stage(1, NK - 1); loadB(g1, u1, NK - 1);
  asm volatile("s_waitcnt vmcnt(12)" ::: "memory");
  asm volatile("s_barrier" ::: "memory");
  compute(0, g0, u0);
  asm volatile("s_barrier" ::: "memory");
  asm volatile("s_waitcnt vmcnt(0)" ::: "memory");
  asm volatile("s_barrier" ::: "memory");
  compute(1, g1, u1);

#pragma unroll
  for (int mi = 0; mi < 4; ++mi)
#pragma unroll
    for (int ni = 0; ni < 2; ++ni)
#pragma unroll
      for (int j = 0; j < 4; ++j) {
        int r = wr + mi * 16 + fq * 4 + j;
        if (r < rows) {
          float g = accg[mi][ni][j], u = accu[mi][ni][j];
          float a = (g / (1.f + __expf(-g))) * u;
          act[(size_t)(off + mb * 128 + r) * DFF + (c0 + wc + ni * 16 + fr)] = f2bf(a);
        }
      }
}

// ---------------- K7: grouped GEMM down (tile 128x64, 4 waves) -> ypair -----------
__global__ __launch_bounds__(256) void down6_k(
    const unsigned short* __restrict__ act, const unsigned short* __restrict__ wdp,
    const int* __restrict__ cnt, const int* __restrict__ offs,
    float* __restrict__ ypair, int e_fixed, int nw, int nbcnt, size_t wstride)
{
  const int x = blockIdx.x;
  const int wti = x % nw, mb = x / nw;
  int e, nb;
  if (e_fixed >= 0) { e = e_fixed; nb = wti; }
  else { e = wti / nbcnt; nb = wti % nbcnt; }
  const int count = cnt[e];
  if (mb * 128 >= count) return;
  const int off = offs[e];
  const int rows = min(128, count - mb * 128);
  const int c0 = nb * 64;

  __shared__ unsigned short As[2][128 * 64];

  const int t = threadIdx.x;
  const int w = t >> 6, l = t & 63;
  const int rbase = w * 8 + (l >> 3);
  const int sc = ((l & 7) ^ (l >> 3)) * 8;

  const unsigned short* aP[4];
#pragma unroll
  for (int i = 0; i < 4; ++i)
    aP[i] = act + (size_t)(off + mb * 128 + i * 32 + rbase) * DFF + sc;

  const size_t wb = (e_fixed >= 0) ? 0 : (size_t)e * wstride;
  const int fr = l & 15, fq = l >> 4;
  const int wr = (w >> 1) * 64, wc = (w & 1) * 32;
  const unsigned short* bdB[2];
#pragma unroll
  for (int ni = 0; ni < 2; ++ni) {
    int fb = (c0 + wc) / 16 + ni;
    bdB[ni] = wdp + wb + (size_t)fb * (DFF / 32) * 512 + l * 8;
  }

  f32x4 acc[4][2];
#pragma unroll
  for (int i = 0; i < 4; ++i)
#pragma unroll
    for (int j = 0; j < 2; ++j) acc[i][j] = (f32x4){0.f, 0.f, 0.f, 0.f};

  auto stage = [&](int b, int k) {
#pragma unroll
    for (int i = 0; i < 4; ++i)
      gl2lds16(aP[i] + k * 64, &As[b][(i * 32 + w * 8) * 64]);
  };
  auto loadB = [&](short8 (&bd)[2][2], int k) {
#pragma unroll
    for (int kk = 0; kk < 2; ++kk)
#pragma unroll
      for (int ni = 0; ni < 2; ++ni)
        bd[ni][kk] = *(const short8*)(bdB[ni] + (size_t)(k * 2 + kk) * 512);
  };
  auto compute = [&](int b, short8 (&bd)[2][2]) {
    short8 af[4][2];
#pragma unroll
    for (int kk = 0; kk < 2; ++kk) {
      const int ch = ((kk * 4 + fq) ^ (fr & 7)) * 8;
#pragma unroll
      for (int mi = 0; mi < 4; ++mi)
        af[mi][kk] = *(const short8*)&As[b][(wr + mi * 16 + fr) * 64 + ch];
    }
    __builtin_amdgcn_s_setprio(1);
#pragma unroll
    for (int kk = 0; kk < 2; ++kk)
#pragma unroll
      for (int mi = 0; mi < 4; ++mi)
#pragma unroll
        for (int ni = 0; ni < 2; ++ni)
          acc[mi][ni] = __builtin_amdgcn_mfma_f32_16x16x32_bf16(af[mi][kk], bd[ni][kk], acc[mi][ni], 0, 0, 0);
    __builtin_amdgcn_s_setprio(0);
  };

  short8 d0[2][2], d1[2][2];
  const int NK = DFF / 64;   // 22 (even)
  stage(0, 0); loadB(d0, 0);
  for (int k = 0; k + 2 < NK; k += 2) {
    stage(1, k + 1); loadB(d1, k + 1);
    asm volatile("s_waitcnt vmcnt(8)" ::: "memory");
    asm volatile("s_barrier" ::: "memory");
    compute(0, d0);
    asm volatile("s_barrier" ::: "memory");
    stage(0, k + 2); loadB(d0, k + 2);
    asm volatile("s_waitcnt vmcnt(8)" ::: "memory");
    asm volatile("s_barrier" ::: "memory");
    compute(1, d1);
    asm volatile("s_barrier" ::: "memory");
  }
  stage(1, NK - 1); loadB(d1, NK - 1);
  asm volatile("s_waitcnt vmcnt(8)" ::: "memory");
  asm volatile("s_barrier" ::: "memory");
  compute(0, d0);
  asm volatile("s_barrier" ::: "memory");
  asm volatile("s_waitcnt vmcnt(0)" ::: "memory");
  asm volatile("s_barrier" ::: "memory");
  compute(1, d1);

#pragma unroll
  for (int mi = 0; mi < 4; ++mi)
#pragma unroll
    for (int ni = 0; ni < 2; ++ni)
#pragma unroll
      for (int j = 0; j < 4; ++j) {
        int r = wr + mi * 16 + fq * 4 + j;
        if (r < rows)
          ypair[(size_t)(off + mb * 128 + r) * HID + (c0 + wc + ni * 16 + fr)] = acc[mi][ni][j];
      }
}

// ---------------- K8: weighted combine ----------------
__global__ __launch_bounds__(256) void combine_k(
    const float* __restrict__ ypair, const int* __restrict__ tok_slot,
    const float* __restrict__ topk_w, float* __restrict__ out)
{
  int i = blockIdx.x * 256 + threadIdx.x;
  int n = i >> 9;
  int dv = (i & 511) * 4;
  int s0 = tok_slot[n * 2], s1 = tok_slot[n * 2 + 1];
  float w0 = topk_w[n * 2], w1 = topk_w[n * 2 + 1];
  float4 a = *(const float4*)&ypair[(size_t)s0 * HID + dv];
  float4 b = *(const float4*)&ypair[(size_t)s1 * HID + dv];
  float4 o;
  o.x = w0 * a.x + w1 * b.x; o.y = w0 * a.y + w1 * b.y;
  o.z = w0 * a.z + w1 * b.z; o.w = w0 * a.w + w1 * b.w;
  *(float4*)&out[(size_t)n * HID + dv] = o;
}

extern "C" void kernel_launch(void* const* d_in, const int* in_sizes, int n_in,
                              void* d_out, int out_size, void* d_ws, size_t ws_size,
                              hipStream_t stream) {
  const float* h  = (const float*)d_in[0];
  const float* gw = (const float*)d_in[1];
  const float* wg = (const float*)d_in[2];
  const float* wu = (const float*)d_in[3];
  const float* wd = (const float*)d_in[4];
  float* out = (float*)d_out;

  const size_t SL = (size_t)DFF * HID;
  char* ws = (char*)d_ws;
  int*   cnt        = (int*)(ws + 0);
  int*   offs       = (int*)(ws + 32);
  int*   cursor     = (int*)(ws + 64);
  int*   pair_token = (int*)(ws + 256);
  float* pair_w     = (float*)(ws + 16640);
  int*   tok_slot   = (int*)(ws + 33024);
  int*   topk_idx   = (int*)(ws + 49408);
  float* topk_w     = (float*)(ws + 65792);
  unsigned short* act = (unsigned short*)(ws + 82176);                // 11,534,336
  unsigned short* hbf = (unsigned short*)(ws + 11616512);             //  8,388,608
  unsigned short* wgt = (unsigned short*)(ws + 20005120);             // 46,137,344 (later wd-pack)
  unsigned short* wut = (unsigned short*)(ws + 66142464);             // 46,137,344
  float* ypair_full   = (float*)(ws + 66142464);                      // aliases wut (down phase)
  const size_t NEED_FULL = 112279808ull;

  hipMemsetAsync(ws, 0, 256, stream);

  gate_topk_k<<<N_TOK / 4, 256, 0, stream>>>(h, gw, cnt, topk_idx, topk_w);
  prefix_k<<<1, 64, 0, stream>>>(cnt, offs, cursor);
  scatter_k<<<N_TOK / 256, 256, 0, stream>>>(topk_idx, topk_w, cursor, pair_token, pair_w, tok_slot);
  convert_h_k<<<(N_TOK * HID / 8) / 256, 256, 0, stream>>>(h, hbf);

  if (ws_size >= NEED_FULL) {
    fragpack_k<<<dim3(HID / 64, DFF / 64, 16), 256, 0, stream>>>(wg, wgt, wu, wut, HID, DFF, 8);
    gateup6_k<<<176 * 16, 256, 0, stream>>>(hbf, wgt, wut, cnt, offs, pair_token, act,
                                            -1, 176, 22, SL);
    fragpack_k<<<dim3(DFF / 64, HID / 64, 8), 256, 0, stream>>>(wd, wgt, wd, wgt, DFF, HID, 8);
    down6_k<<<256 * 16, 256, 0, stream>>>(act, wgt, cnt, offs, ypair_full,
                                          -1, 256, 32, SL);
    combine_k<<<(N_TOK * HID / 4) / 256, 256, 0, stream>>>(ypair_full, tok_slot, topk_w, out);
  } else {
    unsigned short* wgtE = (unsigned short*)(ws + 20005120);
    unsigned short* wutE = (unsigned short*)(ws + 25772288);
    float* ypair = (float*)(ws + 31539456);
    for (int e = 0; e < NEXP; ++e) {
      fragpack_k<<<dim3(HID / 64, DFF / 64, 2), 256, 0, stream>>>(wg + e * SL, wgtE, wu + e * SL, wutE, HID, DFF, 1);
      gateup6_k<<<22 * 16, 256, 0, stream>>>(hbf, wgtE, wutE, cnt, offs, pair_token, act,
                                             e, 22, 22, 0);
    }
    for (int e = 0; e < NEXP; ++e) {
      fragpack_k<<<dim3(DFF / 64, HID / 64, 1), 256, 0, stream>>>(wd + e * SL, wgtE, wd + e * SL, wgtE, DFF, HID, 1);
      down6_k<<<32 * 16, 256, 0, stream>>>(act, wgtE, cnt, offs, ypair, e, 32, 32, 0);
    }
    combine_k<<<(N_TOK * HID / 4) / 256, 256, 0, stream>>>(ypair, tok_slot, topk_w, out);
  }
}

// Round 7
// 330.392 us; speedup vs baseline: 1.0708x; 1.0708x over previous
//
#include <hip/hip_runtime.h>
#include <hip/hip_bf16.h>
#include <stdint.h>

#define N_TOK 2048
#define HID   2048
#define NEXP  8
#define DFF   1408

typedef __attribute__((ext_vector_type(8))) short short8;
typedef __attribute__((ext_vector_type(4))) float f32x4;

__device__ __forceinline__ unsigned short f2bf(float f) {
  union { float ff; uint32_t u; } v; v.ff = f;
  return (unsigned short)((v.u + 0x7FFFu + ((v.u >> 16) & 1u)) >> 16);
}

__device__ __forceinline__ void gl2lds16(const void* g, void* l) {
  __builtin_amdgcn_global_load_lds(
      (const __attribute__((address_space(1))) void*)g,
      (__attribute__((address_space(3))) void*)l, 16, 0, 0);
}

#define MFMA16(a, b, c) __builtin_amdgcn_mfma_f32_16x16x32_bf16((a), (b), (c), 0, 0, 0)

// ---------------- K1: gating ----------------
__global__ __launch_bounds__(256) void gate_topk_k(
    const float* __restrict__ h, const float* __restrict__ gw,
    int* __restrict__ cnt, int* __restrict__ topk_idx, float* __restrict__ topk_w)
{
  int token = blockIdx.x * 4 + (threadIdx.x >> 6);
  int lane  = threadIdx.x & 63;
  const float* hr = h + (size_t)token * HID;
  float acc[NEXP];
#pragma unroll
  for (int e = 0; e < NEXP; ++e) acc[e] = 0.f;
  for (int i = lane; i < HID; i += 64) {
    float hv = hr[i];
#pragma unroll
    for (int e = 0; e < NEXP; ++e) acc[e] = fmaf(hv, gw[e * HID + i], acc[e]);
  }
#pragma unroll
  for (int e = 0; e < NEXP; ++e) {
    float a = acc[e];
#pragma unroll
    for (int s = 32; s > 0; s >>= 1) a += __shfl_xor(a, s, 64);
    acc[e] = a;
  }
  if (lane == 0) {
    float m = acc[0];
#pragma unroll
    for (int e = 1; e < NEXP; ++e) m = fmaxf(m, acc[e]);
    float w[NEXP]; float s = 0.f;
#pragma unroll
    for (int e = 0; e < NEXP; ++e) { w[e] = __expf(acc[e] - m); s += w[e]; }
    float inv = 1.f / s;
    int i0 = 0; float b0 = acc[0];
#pragma unroll
    for (int e = 1; e < NEXP; ++e) if (acc[e] > b0) { b0 = acc[e]; i0 = e; }
    int i1 = -1; float b1 = -3.4e38f;
#pragma unroll
    for (int e = 0; e < NEXP; ++e) if (e != i0 && acc[e] > b1) { b1 = acc[e]; i1 = e; }
    topk_idx[token * 2 + 0] = i0;
    topk_idx[token * 2 + 1] = i1;
    topk_w[token * 2 + 0] = w[i0] * inv;
    topk_w[token * 2 + 1] = w[i1] * inv;
    atomicAdd(&cnt[i0], 1);
    atomicAdd(&cnt[i1], 1);
  }
}

// ---------------- K2: prefix ----------------
__global__ void prefix_k(const int* __restrict__ cnt, int* __restrict__ offs,
                         int* __restrict__ cursor) {
  if (threadIdx.x == 0 && blockIdx.x == 0) {
    int s = 0;
    for (int e = 0; e < NEXP; ++e) { offs[e] = s; cursor[e] = s; s += cnt[e]; }
  }
}

// ---------------- K3: scatter (+ inverse map tok_slot) ----------------
__global__ __launch_bounds__(256) void scatter_k(
    const int* __restrict__ topk_idx, const float* __restrict__ topk_w,
    int* __restrict__ cursor, int* __restrict__ pair_token, float* __restrict__ pair_w,
    int* __restrict__ tok_slot)
{
  int n = blockIdx.x * 256 + threadIdx.x;
  if (n >= N_TOK) return;
#pragma unroll
  for (int k = 0; k < 2; ++k) {
    int e = topk_idx[n * 2 + k];
    int p = atomicAdd(&cursor[e], 1);
    pair_token[p] = n;
    pair_w[p] = topk_w[n * 2 + k];
    tok_slot[n * 2 + k] = p;
  }
}

// ---------------- K4: h fp32 -> bf16 ----------------
__global__ __launch_bounds__(256) void convert_h_k(const float* __restrict__ src,
                                                   unsigned short* __restrict__ dst) {
  int i = blockIdx.x * 256 + threadIdx.x;
  float4 a = ((const float4*)src)[(size_t)i * 2];
  float4 b = ((const float4*)src)[(size_t)i * 2 + 1];
  unsigned short o[8] = {f2bf(a.x), f2bf(a.y), f2bf(a.z), f2bf(a.w),
                         f2bf(b.x), f2bf(b.y), f2bf(b.z), f2bf(b.w)};
  *(short8*)&dst[(size_t)i * 8] = *(const short8*)o;
}

// ---------------- K5: transpose-convert fp32 [z][R][C] -> bf16 [z][C][R] ----------------
__global__ __launch_bounds__(256) void transpose_k(const float* __restrict__ s1,
                                                   unsigned short* __restrict__ d1,
                                                   const float* __restrict__ s2,
                                                   unsigned short* __restrict__ d2,
                                                   int R, int C, int nz1)
{
  __shared__ unsigned short T[64 * 66];
  const size_t sl = (size_t)R * C;
  int z = blockIdx.z;
  const float* s; unsigned short* d;
  if (z < nz1) { s = s1 + (size_t)z * sl; d = d1 + (size_t)z * sl; }
  else { s = s2 + (size_t)(z - nz1) * sl; d = d2 + (size_t)(z - nz1) * sl; }
  const int rb = blockIdx.x * 64, cb = blockIdx.y * 64;
  const int t = threadIdx.x;
  const int tr = t >> 4, tc = (t & 15) * 4;
  const float* sp = s + (size_t)(rb + tr) * C + cb + tc;
#pragma unroll
  for (int i = 0; i < 4; ++i) {
    float4 v = *(const float4*)(sp + (size_t)i * 16 * C);
    int r = tr + i * 16;
    uint32_t p0 = (uint32_t)f2bf(v.x) | ((uint32_t)f2bf(v.y) << 16);
    uint32_t p1 = (uint32_t)f2bf(v.z) | ((uint32_t)f2bf(v.w) << 16);
    *(uint32_t*)&T[r * 66 + tc]     = p0;
    *(uint32_t*)&T[r * 66 + tc + 2] = p1;
  }
  __syncthreads();
  const int f = t >> 2, ch = (t & 3) * 16;
  unsigned short* dp = d + (size_t)(cb + f) * R + rb + ch;
#pragma unroll
  for (int g = 0; g < 2; ++g) {
    unsigned short buf[8];
#pragma unroll
    for (int j = 0; j < 8; ++j) buf[j] = T[(ch + g * 8 + j) * 66 + f];
    *(short8*)(dp + g * 8) = *(const short8*)buf;
  }
}

// ---------------- K6: grouped GEMM gate+up (128x128xBK64, 8 waves) ----------------
// Triple-buffered LDS, 2-tiles-ahead prefetch (vmcnt(12) steady state), 4-phase
// compute (kk x mi-half) with per-phase barrier + setprio around MFMA cluster.
__global__ __launch_bounds__(512) void gateup7_k(
    const unsigned short* __restrict__ hbf,
    const unsigned short* __restrict__ wgt, const unsigned short* __restrict__ wut,
    const int* __restrict__ cnt, const int* __restrict__ offs,
    const int* __restrict__ pair_token, unsigned short* __restrict__ act,
    int e_fixed, int nw, int nbcnt, size_t wstride)
{
  const int x = blockIdx.x;
  const int wti = x % nw, mb = x / nw;
  int e, nb;
  if (e_fixed >= 0) { e = e_fixed; nb = wti; }
  else { e = wti / nbcnt; nb = wti % nbcnt; }
  const int count = cnt[e];
  if (mb * 128 >= count) return;
  const int off = offs[e];
  const int rows = min(128, count - mb * 128);
  const int c0 = nb * 128;

  __shared__ unsigned short As[3][128 * 64];
  __shared__ unsigned short Bg[3][128 * 64];
  __shared__ unsigned short Bu[3][128 * 64];
  __shared__ int tok[128];

  const int t = threadIdx.x;
  if (t < 128) tok[t] = pair_token[off + mb * 128 + min(t, rows - 1)];
  __syncthreads();

  const int w = t >> 6, l = t & 63;
  const int sr = l >> 3;
  const int sc = ((l & 7) ^ sr) * 8;
  const int r0 = w * 16 + sr, r1 = w * 16 + 8 + sr;

  const size_t wb = (e_fixed >= 0) ? 0 : (size_t)e * wstride;
  const unsigned short* wgE = wgt + wb;
  const unsigned short* wuE = wut + wb;
  const unsigned short* aP0 = hbf + (size_t)tok[r0] * HID + sc;
  const unsigned short* aP1 = hbf + (size_t)tok[r1] * HID + sc;
  const unsigned short* gP0 = wgE + (size_t)(c0 + r0) * HID + sc;
  const unsigned short* gP1 = wgE + (size_t)(c0 + r1) * HID + sc;
  const unsigned short* uP0 = wuE + (size_t)(c0 + r0) * HID + sc;
  const unsigned short* uP1 = wuE + (size_t)(c0 + r1) * HID + sc;
  const int ldsLo = (w * 16) * 64, ldsHi = (w * 16 + 8) * 64;

  const int fr = l & 15, fq = l >> 4;
  const int wr = (w >> 2) * 64, wc = (w & 3) * 32;
  const int f3 = fr & 7;
  const int ch0 = (fq ^ f3) * 8;
  const int ch1 = ((4 + fq) ^ f3) * 8;

  f32x4 accg[4][2], accu[4][2];
#pragma unroll
  for (int i = 0; i < 4; ++i)
#pragma unroll
    for (int j = 0; j < 2; ++j) {
      accg[i][j] = (f32x4){0.f, 0.f, 0.f, 0.f};
      accu[i][j] = (f32x4){0.f, 0.f, 0.f, 0.f};
    }

  auto stage = [&](int b, int kt) {
    gl2lds16(aP0 + kt, &As[b][ldsLo]); gl2lds16(aP1 + kt, &As[b][ldsHi]);
    gl2lds16(gP0 + kt, &Bg[b][ldsLo]); gl2lds16(gP1 + kt, &Bg[b][ldsHi]);
    gl2lds16(uP0 + kt, &Bu[b][ldsLo]); gl2lds16(uP1 + kt, &Bu[b][ldsHi]);
  };

  auto compute4 = [&](int b) {
    const unsigned short* as = As[b];
    const unsigned short* gs = Bg[b];
    const unsigned short* us = Bu[b];
    short8 a0, a1, g0, g1, u0, u1;
    // ---- P0: kk0, mi 0-1 (loads B for kk0) ----
    a0 = *(const short8*)&as[(wr + fr) * 64 + ch0];
    a1 = *(const short8*)&as[(wr + 16 + fr) * 64 + ch0];
    g0 = *(const short8*)&gs[(wc + fr) * 64 + ch0];
    g1 = *(const short8*)&gs[(wc + 16 + fr) * 64 + ch0];
    u0 = *(const short8*)&us[(wc + fr) * 64 + ch0];
    u1 = *(const short8*)&us[(wc + 16 + fr) * 64 + ch0];
    __builtin_amdgcn_s_barrier();
    __builtin_amdgcn_s_setprio(1);
    accg[0][0] = MFMA16(a0, g0, accg[0][0]); accu[0][0] = MFMA16(a0, u0, accu[0][0]);
    accg[0][1] = MFMA16(a0, g1, accg[0][1]); accu[0][1] = MFMA16(a0, u1, accu[0][1]);
    accg[1][0] = MFMA16(a1, g0, accg[1][0]); accu[1][0] = MFMA16(a1, u0, accu[1][0]);
    accg[1][1] = MFMA16(a1, g1, accg[1][1]); accu[1][1] = MFMA16(a1, u1, accu[1][1]);
    __builtin_amdgcn_s_setprio(0);
    __builtin_amdgcn_sched_barrier(0);
    // ---- P1: kk0, mi 2-3 (B reused) ----
    a0 = *(const short8*)&as[(wr + 32 + fr) * 64 + ch0];
    a1 = *(const short8*)&as[(wr + 48 + fr) * 64 + ch0];
    __builtin_amdgcn_s_barrier();
    __builtin_amdgcn_s_setprio(1);
    accg[2][0] = MFMA16(a0, g0, accg[2][0]); accu[2][0] = MFMA16(a0, u0, accu[2][0]);
    accg[2][1] = MFMA16(a0, g1, accg[2][1]); accu[2][1] = MFMA16(a0, u1, accu[2][1]);
    accg[3][0] = MFMA16(a1, g0, accg[3][0]); accu[3][0] = MFMA16(a1, u0, accu[3][0]);
    accg[3][1] = MFMA16(a1, g1, accg[3][1]); accu[3][1] = MFMA16(a1, u1, accu[3][1]);
    __builtin_amdgcn_s_setprio(0);
    __builtin_amdgcn_sched_barrier(0);
    // ---- P2: kk1, mi 0-1 (loads B for kk1) ----
    a0 = *(const short8*)&as[(wr + fr) * 64 + ch1];
    a1 = *(const short8*)&as[(wr + 16 + fr) * 64 + ch1];
    g0 = *(const short8*)&gs[(wc + fr) * 64 + ch1];
    g1 = *(const short8*)&gs[(wc + 16 + fr) * 64 + ch1];
    u0 = *(const short8*)&us[(wc + fr) * 64 + ch1];
    u1 = *(const short8*)&us[(wc + 16 + fr) * 64 + ch1];
    __builtin_amdgcn_s_barrier();
    __builtin_amdgcn_s_setprio(1);
    accg[0][0] = MFMA16(a0, g0, accg[0][0]); accu[0][0] = MFMA16(a0, u0, accu[0][0]);
    accg[0][1] = MFMA16(a0, g1, accg[0][1]); accu[0][1] = MFMA16(a0, u1, accu[0][1]);
    accg[1][0] = MFMA16(a1, g0, accg[1][0]); accu[1][0] = MFMA16(a1, u0, accu[1][0]);
    accg[1][1] = MFMA16(a1, g1, accg[1][1]); accu[1][1] = MFMA16(a1, u1, accu[1][1]);
    __builtin_amdgcn_s_setprio(0);
    __builtin_amdgcn_sched_barrier(0);
    // ---- P3: kk1, mi 2-3 ----
    a0 = *(const short8*)&as[(wr + 32 + fr) * 64 + ch1];
    a1 = *(const short8*)&as[(wr + 48 + fr) * 64 + ch1];
    __builtin_amdgcn_s_barrier();
    __builtin_amdgcn_s_setprio(1);
    accg[2][0] = MFMA16(a0, g0, accg[2][0]); accu[2][0] = MFMA16(a0, u0, accu[2][0]);
    accg[2][1] = MFMA16(a0, g1, accg[2][1]); accu[2][1] = MFMA16(a0, u1, accu[2][1]);
    accg[3][0] = MFMA16(a1, g0, accg[3][0]); accu[3][0] = MFMA16(a1, u0, accu[3][0]);
    accg[3][1] = MFMA16(a1, g1, accg[3][1]); accu[3][1] = MFMA16(a1, u1, accu[3][1]);
    __builtin_amdgcn_s_setprio(0);
    __builtin_amdgcn_sched_barrier(0);
  };

  const int NK = HID / 64;     // 32
  stage(0, 0); stage(1, 64);   // 12 outstanding
  int bc = 0;
  for (int k = 0; k < NK; ++k) {
    if (k + 2 < NK) {
      int bn = bc + 2; if (bn >= 3) bn -= 3;
      stage(bn, (k + 2) * 64);                       // +6 -> 18 outstanding
      asm volatile("s_waitcnt vmcnt(12)" ::: "memory");  // tile-k loads done
    } else if (k + 1 < NK) {
      asm volatile("s_waitcnt vmcnt(6)" ::: "memory");
    } else {
      asm volatile("s_waitcnt vmcnt(0)" ::: "memory");
    }
    __builtin_amdgcn_s_barrier();
    compute4(bc);
    bc = (bc == 2) ? 0 : bc + 1;
  }

#pragma unroll
  for (int mi = 0; mi < 4; ++mi)
#pragma unroll
    for (int ni = 0; ni < 2; ++ni)
#pragma unroll
      for (int j = 0; j < 4; ++j) {
        int r = wr + mi * 16 + fq * 4 + j;
        if (r < rows) {
          float g = accg[mi][ni][j], u = accu[mi][ni][j];
          float a = (g / (1.f + __expf(-g))) * u;
          act[(size_t)(off + mb * 128 + r) * DFF + (c0 + wc + ni * 16 + fr)] = f2bf(a);
        }
      }
}

// ---------------- K7: grouped GEMM down (dbuf + 4-phase + vmcnt(8)) -> ypair ------
__global__ __launch_bounds__(256) void down7_k(
    const unsigned short* __restrict__ act, const unsigned short* __restrict__ wdt,
    const int* __restrict__ cnt, const int* __restrict__ offs,
    float* __restrict__ ypair, int e_fixed, int nw, int nbcnt, size_t wstride)
{
  const int x = blockIdx.x;
  const int wti = x % nw, mb = x / nw;
  int e, nb;
  if (e_fixed >= 0) { e = e_fixed; nb = wti; }
  else { e = wti / nbcnt; nb = wti % nbcnt; }
  const int count = cnt[e];
  if (mb * 128 >= count) return;
  const int off = offs[e];
  const int rows = min(128, count - mb * 128);
  const int c0 = nb * 128;

  __shared__ unsigned short As[2][128 * 64];
  __shared__ unsigned short Bd[2][128 * 64];

  const int t = threadIdx.x;
  const int w = t >> 6, l = t & 63;
  const int sr = l >> 3;
  const int sc = ((l & 7) ^ sr) * 8;
  const size_t wb = (e_fixed >= 0) ? 0 : (size_t)e * wstride;
  const unsigned short* wdE = wdt + wb;

  const unsigned short* aP[4];
  const unsigned short* bP[4];
  int ldsB[4];
#pragma unroll
  for (int i = 0; i < 4; ++i) {
    int rr = w * 32 + i * 8 + sr;
    aP[i] = act + (size_t)(off + mb * 128 + rr) * DFF + sc;
    bP[i] = wdE + (size_t)(c0 + rr) * DFF + sc;
    ldsB[i] = (w * 32 + i * 8) * 64;
  }

  const int fr = l & 15, fq = l >> 4;
  const int wr = (w >> 1) * 64, wc = (w & 1) * 64;
  const int f3 = fr & 7;
  const int ch0 = (fq ^ f3) * 8;
  const int ch1 = ((4 + fq) ^ f3) * 8;

  f32x4 acc[4][4];
#pragma unroll
  for (int i = 0; i < 4; ++i)
#pragma unroll
    for (int j = 0; j < 4; ++j) acc[i][j] = (f32x4){0.f, 0.f, 0.f, 0.f};

  auto stage = [&](int b, int kt) {
#pragma unroll
    for (int i = 0; i < 4; ++i) {
      gl2lds16(aP[i] + kt, &As[b][ldsB[i]]);
      gl2lds16(bP[i] + kt, &Bd[b][ldsB[i]]);
    }
  };

  auto compute4 = [&](int b) {
    const unsigned short* as = As[b];
    const unsigned short* ds = Bd[b];
    short8 a0, a1, d0, d1, d2, d3;
    // P0: kk0 mi0-1 + B kk0
    a0 = *(const short8*)&as[(wr + fr) * 64 + ch0];
    a1 = *(const short8*)&as[(wr + 16 + fr) * 64 + ch0];
    d0 = *(const short8*)&ds[(wc + fr) * 64 + ch0];
    d1 = *(const short8*)&ds[(wc + 16 + fr) * 64 + ch0];
    d2 = *(const short8*)&ds[(wc + 32 + fr) * 64 + ch0];
    d3 = *(const short8*)&ds[(wc + 48 + fr) * 64 + ch0];
    __builtin_amdgcn_s_barrier();
    __builtin_amdgcn_s_setprio(1);
    acc[0][0] = MFMA16(a0, d0, acc[0][0]); acc[0][1] = MFMA16(a0, d1, acc[0][1]);
    acc[0][2] = MFMA16(a0, d2, acc[0][2]); acc[0][3] = MFMA16(a0, d3, acc[0][3]);
    acc[1][0] = MFMA16(a1, d0, acc[1][0]); acc[1][1] = MFMA16(a1, d1, acc[1][1]);
    acc[1][2] = MFMA16(a1, d2, acc[1][2]); acc[1][3] = MFMA16(a1, d3, acc[1][3]);
    __builtin_amdgcn_s_setprio(0);
    __builtin_amdgcn_sched_barrier(0);
    // P1: kk0 mi2-3
    a0 = *(const short8*)&as[(wr + 32 + fr) * 64 + ch0];
    a1 = *(const short8*)&as[(wr + 48 + fr) * 64 + ch0];
    __builtin_amdgcn_s_barrier();
    __builtin_amdgcn_s_setprio(1);
    acc[2][0] = MFMA16(a0, d0, acc[2][0]); acc[2][1] = MFMA16(a0, d1, acc[2][1]);
    acc[2][2] = MFMA16(a0, d2, acc[2][2]); acc[2][3] = MFMA16(a0, d3, acc[2][3]);
    acc[3][0] = MFMA16(a1, d0, acc[3][0]); acc[3][1] = MFMA16(a1, d1, acc[3][1]);
    acc[3][2] = MFMA16(a1, d2, acc[3][2]); acc[3][3] = MFMA16(a1, d3, acc[3][3]);
    __builtin_amdgcn_s_setprio(0);
    __builtin_amdgcn_sched_barrier(0);
    // P2: kk1 mi0-1 + B kk1
    a0 = *(const short8*)&as[(wr + fr) * 64 + ch1];
    a1 = *(const short8*)&as[(wr + 16 + fr) * 64 + ch1];
    d0 = *(const short8*)&ds[(wc + fr) * 64 + ch1];
    d1 = *(const short8*)&ds[(wc + 16 + fr) * 64 + ch1];
    d2 = *(const short8*)&ds[(wc + 32 + fr) * 64 + ch1];
    d3 = *(const short8*)&ds[(wc + 48 + fr) * 64 + ch1];
    __builtin_amdgcn_s_barrier();
    __builtin_amdgcn_s_setprio(1);
    acc[0][0] = MFMA16(a0, d0, acc[0][0]); acc[0][1] = MFMA16(a0, d1, acc[0][1]);
    acc[0][2] = MFMA16(a0, d2, acc[0][2]); acc[0][3] = MFMA16(a0, d3, acc[0][3]);
    acc[1][0] = MFMA16(a1, d0, acc[1][0]); acc[1][1] = MFMA16(a1, d1, acc[1][1]);
    acc[1][2] = MFMA16(a1, d2, acc[1][2]); acc[1][3] = MFMA16(a1, d3, acc[1][3]);
    __builtin_amdgcn_s_setprio(0);
    __builtin_amdgcn_sched_barrier(0);
    // P3: kk1 mi2-3
    a0 = *(const short8*)&as[(wr + 32 + fr) * 64 + ch1];
    a1 = *(const short8*)&as[(wr + 48 + fr) * 64 + ch1];
    __builtin_amdgcn_s_barrier();
    __builtin_amdgcn_s_setprio(1);
    acc[2][0] = MFMA16(a0, d0, acc[2][0]); acc[2][1] = MFMA16(a0, d1, acc[2][1]);
    acc[2][2] = MFMA16(a0, d2, acc[2][2]); acc[2][3] = MFMA16(a0, d3, acc[2][3]);
    acc[3][0] = MFMA16(a1, d0, acc[3][0]); acc[3][1] = MFMA16(a1, d1, acc[3][1]);
    acc[3][2] = MFMA16(a1, d2, acc[3][2]); acc[3][3] = MFMA16(a1, d3, acc[3][3]);
    __builtin_amdgcn_s_setprio(0);
    __builtin_amdgcn_sched_barrier(0);
  };

  const int NK = DFF / 64;     // 22
  stage(0, 0);
  int cur = 0;
  for (int k = 0; k < NK; ++k) {
    if (k + 1 < NK) {
      stage(cur ^ 1, (k + 1) * 64);
      asm volatile("s_waitcnt vmcnt(8)" ::: "memory");
    } else {
      asm volatile("s_waitcnt vmcnt(0)" ::: "memory");
    }
    __builtin_amdgcn_s_barrier();
    compute4(cur);
    __builtin_amdgcn_s_barrier();   // WAR: all reads of cur done before next stage
    cur ^= 1;
  }

#pragma unroll
  for (int mi = 0; mi < 4; ++mi)
#pragma unroll
    for (int ni = 0; ni < 4; ++ni)
#pragma unroll
      for (int j = 0; j < 4; ++j) {
        int r = wr + mi * 16 + fq * 4 + j;
        if (r < rows)
          ypair[(size_t)(off + mb * 128 + r) * HID + (c0 + wc + ni * 16 + fr)] = acc[mi][ni][j];
      }
}

// ---------------- K8: weighted combine ----------------
__global__ __launch_bounds__(256) void combine_k(
    const float* __restrict__ ypair, const int* __restrict__ tok_slot,
    const float* __restrict__ topk_w, float* __restrict__ out)
{
  int i = blockIdx.x * 256 + threadIdx.x;
  int n = i >> 9;
  int dv = (i & 511) * 4;
  int s0 = tok_slot[n * 2], s1 = tok_slot[n * 2 + 1];
  float w0 = topk_w[n * 2], w1 = topk_w[n * 2 + 1];
  float4 a = *(const float4*)&ypair[(size_t)s0 * HID + dv];
  float4 b = *(const float4*)&ypair[(size_t)s1 * HID + dv];
  float4 o;
  o.x = w0 * a.x + w1 * b.x; o.y = w0 * a.y + w1 * b.y;
  o.z = w0 * a.z + w1 * b.z; o.w = w0 * a.w + w1 * b.w;
  *(float4*)&out[(size_t)n * HID + dv] = o;
}

extern "C" void kernel_launch(void* const* d_in, const int* in_sizes, int n_in,
                              void* d_out, int out_size, void* d_ws, size_t ws_size,
                              hipStream_t stream) {
  const float* h  = (const float*)d_in[0];
  const float* gw = (const float*)d_in[1];
  const float* wg = (const float*)d_in[2];
  const float* wu = (const float*)d_in[3];
  const float* wd = (const float*)d_in[4];
  float* out = (float*)d_out;

  const size_t SL = (size_t)DFF * HID;
  char* ws = (char*)d_ws;
  int*   cnt        = (int*)(ws + 0);
  int*   offs       = (int*)(ws + 32);
  int*   cursor     = (int*)(ws + 64);
  int*   pair_token = (int*)(ws + 256);
  float* pair_w     = (float*)(ws + 16640);
  int*   tok_slot   = (int*)(ws + 33024);
  int*   topk_idx   = (int*)(ws + 49408);
  float* topk_w     = (float*)(ws + 65792);
  unsigned short* act = (unsigned short*)(ws + 82176);                // 11,534,336
  unsigned short* hbf = (unsigned short*)(ws + 11616512);             //  8,388,608
  unsigned short* wgt = (unsigned short*)(ws + 20005120);             // 46,137,344 (also wd^T)
  unsigned short* wut = (unsigned short*)(ws + 66142464);             // 46,137,344
  float* ypair_full   = (float*)(ws + 66142464);                      // aliases wut (down phase)
  const size_t NEED_FULL = 112279808ull;

  hipMemsetAsync(ws, 0, 256, stream);

  gate_topk_k<<<N_TOK / 4, 256, 0, stream>>>(h, gw, cnt, topk_idx, topk_w);
  prefix_k<<<1, 64, 0, stream>>>(cnt, offs, cursor);
  scatter_k<<<N_TOK / 256, 256, 0, stream>>>(topk_idx, topk_w, cursor, pair_token, pair_w, tok_slot);
  convert_h_k<<<(N_TOK * HID / 8) / 256, 256, 0, stream>>>(h, hbf);

  if (ws_size >= NEED_FULL) {
    transpose_k<<<dim3(HID / 64, DFF / 64, 16), 256, 0, stream>>>(wg, wgt, wu, wut, HID, DFF, 8);
    gateup7_k<<<88 * 16, 512, 0, stream>>>(hbf, wgt, wut, cnt, offs, pair_token, act,
                                           -1, 88, 11, SL);
    transpose_k<<<dim3(DFF / 64, HID / 64, 8), 256, 0, stream>>>(wd, wgt, wd, wgt, DFF, HID, 8);
    down7_k<<<128 * 16, 256, 0, stream>>>(act, wgt, cnt, offs, ypair_full,
                                          -1, 128, 16, SL);
    combine_k<<<(N_TOK * HID / 4) / 256, 256, 0, stream>>>(ypair_full, tok_slot, topk_w, out);
  } else {
    unsigned short* wgtE = (unsigned short*)(ws + 20005120);
    unsigned short* wutE = (unsigned short*)(ws + 25772288);
    float* ypair = (float*)(ws + 31539456);
    for (int e = 0; e < NEXP; ++e) {
      transpose_k<<<dim3(HID / 64, DFF / 64, 2), 256, 0, stream>>>(wg + e * SL, wgtE, wu + e * SL, wutE, HID, DFF, 1);
      gateup7_k<<<11 * 16, 512, 0, stream>>>(hbf, wgtE, wutE, cnt, offs, pair_token, act,
                                             e, 11, 11, 0);
    }
    for (int e = 0; e < NEXP; ++e) {
      transpose_k<<<dim3(DFF / 64, HID / 64, 1), 256, 0, stream>>>(wd + e * SL, wgtE, wd + e * SL, wgtE, DFF, HID, 1);
      down7_k<<<16 * 16, 256, 0, stream>>>(act, wgtE, cnt, offs, ypair, e, 16, 16, 0);
    }
    combine_k<<<(N_TOK * HID / 4) / 256, 256, 0, stream>>>(ypair, tok_slot, topk_w, out);
  }
}

// Round 8
// 325.570 us; speedup vs baseline: 1.0866x; 1.0148x over previous
//
#include <hip/hip_runtime.h>
#include <hip/hip_bf16.h>
#include <stdint.h>

#define N_TOK 2048
#define HID   2048
#define NEXP  8
#define DFF   1408

typedef __attribute__((ext_vector_type(8))) short short8;
typedef __attribute__((ext_vector_type(4))) float f32x4;

__device__ __forceinline__ unsigned short f2bf(float f) {
  union { float ff; uint32_t u; } v; v.ff = f;
  return (unsigned short)((v.u + 0x7FFFu + ((v.u >> 16) & 1u)) >> 16);
}

__device__ __forceinline__ void gl2lds16(const void* g, void* l) {
  __builtin_amdgcn_global_load_lds(
      (const __attribute__((address_space(1))) void*)g,
      (__attribute__((address_space(3))) void*)l, 16, 0, 0);
}

#define MFMA16(a, b, c) __builtin_amdgcn_mfma_f32_16x16x32_bf16((a), (b), (c), 0, 0, 0)

// ---------------- K1: gating ----------------
__global__ __launch_bounds__(256) void gate_topk_k(
    const float* __restrict__ h, const float* __restrict__ gw,
    int* __restrict__ cnt, int* __restrict__ topk_idx, float* __restrict__ topk_w)
{
  int token = blockIdx.x * 4 + (threadIdx.x >> 6);
  int lane  = threadIdx.x & 63;
  const float* hr = h + (size_t)token * HID;
  float acc[NEXP];
#pragma unroll
  for (int e = 0; e < NEXP; ++e) acc[e] = 0.f;
  for (int i = lane; i < HID; i += 64) {
    float hv = hr[i];
#pragma unroll
    for (int e = 0; e < NEXP; ++e) acc[e] = fmaf(hv, gw[e * HID + i], acc[e]);
  }
#pragma unroll
  for (int e = 0; e < NEXP; ++e) {
    float a = acc[e];
#pragma unroll
    for (int s = 32; s > 0; s >>= 1) a += __shfl_xor(a, s, 64);
    acc[e] = a;
  }
  if (lane == 0) {
    float m = acc[0];
#pragma unroll
    for (int e = 1; e < NEXP; ++e) m = fmaxf(m, acc[e]);
    float w[NEXP]; float s = 0.f;
#pragma unroll
    for (int e = 0; e < NEXP; ++e) { w[e] = __expf(acc[e] - m); s += w[e]; }
    float inv = 1.f / s;
    int i0 = 0; float b0 = acc[0];
#pragma unroll
    for (int e = 1; e < NEXP; ++e) if (acc[e] > b0) { b0 = acc[e]; i0 = e; }
    int i1 = -1; float b1 = -3.4e38f;
#pragma unroll
    for (int e = 0; e < NEXP; ++e) if (e != i0 && acc[e] > b1) { b1 = acc[e]; i1 = e; }
    topk_idx[token * 2 + 0] = i0;
    topk_idx[token * 2 + 1] = i1;
    topk_w[token * 2 + 0] = w[i0] * inv;
    topk_w[token * 2 + 1] = w[i1] * inv;
    atomicAdd(&cnt[i0], 1);
    atomicAdd(&cnt[i1], 1);
  }
}

// ---------------- K2: prefix ----------------
__global__ void prefix_k(const int* __restrict__ cnt, int* __restrict__ offs,
                         int* __restrict__ cursor) {
  if (threadIdx.x == 0 && blockIdx.x == 0) {
    int s = 0;
    for (int e = 0; e < NEXP; ++e) { offs[e] = s; cursor[e] = s; s += cnt[e]; }
  }
}

// ---------------- K3: scatter (+ inverse map tok_slot) ----------------
__global__ __launch_bounds__(256) void scatter_k(
    const int* __restrict__ topk_idx, const float* __restrict__ topk_w,
    int* __restrict__ cursor, int* __restrict__ pair_token, float* __restrict__ pair_w,
    int* __restrict__ tok_slot)
{
  int n = blockIdx.x * 256 + threadIdx.x;
  if (n >= N_TOK) return;
#pragma unroll
  for (int k = 0; k < 2; ++k) {
    int e = topk_idx[n * 2 + k];
    int p = atomicAdd(&cursor[e], 1);
    pair_token[p] = n;
    pair_w[p] = topk_w[n * 2 + k];
    tok_slot[n * 2 + k] = p;
  }
}

// ---------------- K4: h fp32 -> bf16 ----------------
__global__ __launch_bounds__(256) void convert_h_k(const float* __restrict__ src,
                                                   unsigned short* __restrict__ dst) {
  int i = blockIdx.x * 256 + threadIdx.x;
  float4 a = ((const float4*)src)[(size_t)i * 2];
  float4 b = ((const float4*)src)[(size_t)i * 2 + 1];
  unsigned short o[8] = {f2bf(a.x), f2bf(a.y), f2bf(a.z), f2bf(a.w),
                         f2bf(b.x), f2bf(b.y), f2bf(b.z), f2bf(b.w)};
  *(short8*)&dst[(size_t)i * 8] = *(const short8*)o;
}

// ---------------- K5: transpose-convert fp32 [z][R][C] -> bf16 [z][C][R] ----------------
__global__ __launch_bounds__(256) void transpose_k(const float* __restrict__ s1,
                                                   unsigned short* __restrict__ d1,
                                                   const float* __restrict__ s2,
                                                   unsigned short* __restrict__ d2,
                                                   int R, int C, int nz1)
{
  __shared__ unsigned short T[64 * 66];
  const size_t sl = (size_t)R * C;
  int z = blockIdx.z;
  const float* s; unsigned short* d;
  if (z < nz1) { s = s1 + (size_t)z * sl; d = d1 + (size_t)z * sl; }
  else { s = s2 + (size_t)(z - nz1) * sl; d = d2 + (size_t)(z - nz1) * sl; }
  const int rb = blockIdx.x * 64, cb = blockIdx.y * 64;
  const int t = threadIdx.x;
  const int tr = t >> 4, tc = (t & 15) * 4;
  const float* sp = s + (size_t)(rb + tr) * C + cb + tc;
#pragma unroll
  for (int i = 0; i < 4; ++i) {
    float4 v = *(const float4*)(sp + (size_t)i * 16 * C);
    int r = tr + i * 16;
    uint32_t p0 = (uint32_t)f2bf(v.x) | ((uint32_t)f2bf(v.y) << 16);
    uint32_t p1 = (uint32_t)f2bf(v.z) | ((uint32_t)f2bf(v.w) << 16);
    *(uint32_t*)&T[r * 66 + tc]     = p0;
    *(uint32_t*)&T[r * 66 + tc + 2] = p1;
  }
  __syncthreads();
  const int f = t >> 2, ch = (t & 3) * 16;
  unsigned short* dp = d + (size_t)(cb + f) * R + rb + ch;
#pragma unroll
  for (int g = 0; g < 2; ++g) {
    unsigned short buf[8];
#pragma unroll
    for (int j = 0; j < 8; ++j) buf[j] = T[(ch + g * 8 + j) * 66 + f];
    *(short8*)(dp + g * 8) = *(const short8*)buf;
  }
}

// ---------------- K6: grouped GEMM gate+up (128rows x 64f, 4 waves, dbuf 64KB) ----
// Residency-2 design: 64KB LDS + 256 threads -> 2 blocks/CU; inter-block overlap
// hides the stage/barrier drain (m114 mechanism). nb=22 f-tiles of 64.
__global__ __launch_bounds__(256) void gateup8_k(
    const unsigned short* __restrict__ hbf,
    const unsigned short* __restrict__ wgt, const unsigned short* __restrict__ wut,
    const int* __restrict__ cnt, const int* __restrict__ offs,
    const int* __restrict__ pair_token, unsigned short* __restrict__ act,
    int e_fixed, int nw, int nbcnt, size_t wstride)
{
  const int x = blockIdx.x;
  const int wti = x % nw, mb = x / nw;
  int e, nb;
  if (e_fixed >= 0) { e = e_fixed; nb = wti; }
  else { e = wti / nbcnt; nb = wti % nbcnt; }
  const int count = cnt[e];
  if (mb * 128 >= count) return;
  const int off = offs[e];
  const int rows = min(128, count - mb * 128);
  const int c0 = nb * 64;

  __shared__ unsigned short As[2][128 * 64];
  __shared__ unsigned short Bg[2][64 * 64];
  __shared__ unsigned short Bu[2][64 * 64];
  __shared__ int tok[128];

  const int t = threadIdx.x;
  if (t < 128) tok[t] = pair_token[off + mb * 128 + min(t, rows - 1)];
  __syncthreads();

  const int w = t >> 6, l = t & 63;
  const int sr = l >> 3;
  const int sc = ((l & 7) ^ sr) * 8;

  const size_t wb = (e_fixed >= 0) ? 0 : (size_t)e * wstride;
  const unsigned short* wgE = wgt + wb;
  const unsigned short* wuE = wut + wb;

  const unsigned short* aP[4];
  int ldsA[4];
#pragma unroll
  for (int i = 0; i < 4; ++i) {
    int rr = w * 32 + i * 8 + sr;                 // 128 A-rows
    aP[i] = hbf + (size_t)tok[rr] * HID + sc;
    ldsA[i] = (w * 32 + i * 8) * 64;
  }
  const unsigned short* gP[2];
  const unsigned short* uP[2];
  int ldsB[2];
#pragma unroll
  for (int i = 0; i < 2; ++i) {
    int rb = w * 16 + i * 8 + sr;                 // 64 B-rows (f)
    gP[i] = wgE + (size_t)(c0 + rb) * HID + sc;
    uP[i] = wuE + (size_t)(c0 + rb) * HID + sc;
    ldsB[i] = (w * 16 + i * 8) * 64;
  }

  const int fr = l & 15, fq = l >> 4;
  const int wr = (w >> 1) * 64, wc = (w & 1) * 32; // wave tile 64r x 32f (dual)
  const int f3 = fr & 7;

  f32x4 accg[4][2], accu[4][2];
#pragma unroll
  for (int i = 0; i < 4; ++i)
#pragma unroll
    for (int j = 0; j < 2; ++j) {
      accg[i][j] = (f32x4){0.f, 0.f, 0.f, 0.f};
      accu[i][j] = (f32x4){0.f, 0.f, 0.f, 0.f};
    }

  auto stage = [&](int b, int kt) {
#pragma unroll
    for (int i = 0; i < 4; ++i) gl2lds16(aP[i] + kt, &As[b][ldsA[i]]);
#pragma unroll
    for (int i = 0; i < 2; ++i) {
      gl2lds16(gP[i] + kt, &Bg[b][ldsB[i]]);
      gl2lds16(uP[i] + kt, &Bu[b][ldsB[i]]);
    }
  };
  auto compute = [&](int b) {
    short8 af[4][2], bg[2][2], bu[2][2];
#pragma unroll
    for (int kk = 0; kk < 2; ++kk) {
      const int ch = ((kk * 4 + fq) ^ f3) * 8;
#pragma unroll
      for (int mi = 0; mi < 4; ++mi)
        af[mi][kk] = *(const short8*)&As[b][(wr + mi * 16 + fr) * 64 + ch];
#pragma unroll
      for (int ni = 0; ni < 2; ++ni) {
        bg[ni][kk] = *(const short8*)&Bg[b][(wc + ni * 16 + fr) * 64 + ch];
        bu[ni][kk] = *(const short8*)&Bu[b][(wc + ni * 16 + fr) * 64 + ch];
      }
    }
    __builtin_amdgcn_s_setprio(1);
#pragma unroll
    for (int kk = 0; kk < 2; ++kk)
#pragma unroll
      for (int mi = 0; mi < 4; ++mi)
#pragma unroll
        for (int ni = 0; ni < 2; ++ni) {
          accg[mi][ni] = MFMA16(af[mi][kk], bg[ni][kk], accg[mi][ni]);
          accu[mi][ni] = MFMA16(af[mi][kk], bu[ni][kk], accu[mi][ni]);
        }
    __builtin_amdgcn_s_setprio(0);
  };

  const int NK = HID / 64;     // 32
  stage(0, 0);
  int cur = 0;
  for (int k = 0; k + 1 < NK; ++k) {
    stage(cur ^ 1, (k + 1) * 64);
    asm volatile("s_waitcnt vmcnt(8)" ::: "memory");   // prev tile's 8 loads done
    asm volatile("s_barrier" ::: "memory");
    compute(cur);
    asm volatile("s_barrier" ::: "memory");            // WAR before next overwrite
    cur ^= 1;
  }
  asm volatile("s_waitcnt vmcnt(0)" ::: "memory");
  asm volatile("s_barrier" ::: "memory");
  compute(cur);

#pragma unroll
  for (int mi = 0; mi < 4; ++mi)
#pragma unroll
    for (int ni = 0; ni < 2; ++ni)
#pragma unroll
      for (int j = 0; j < 4; ++j) {
        int r = wr + mi * 16 + fq * 4 + j;
        if (r < rows) {
          float g = accg[mi][ni][j], u = accu[mi][ni][j];
          float a = (g / (1.f + __expf(-g))) * u;
          act[(size_t)(off + mb * 128 + r) * DFF + (c0 + wc + ni * 16 + fr)] = f2bf(a);
        }
      }
}

// ---------------- K7: grouped GEMM down (128x128, 4 waves, dbuf 64KB) -> ypair ----
__global__ __launch_bounds__(256) void down8_k(
    const unsigned short* __restrict__ act, const unsigned short* __restrict__ wdt,
    const int* __restrict__ cnt, const int* __restrict__ offs,
    float* __restrict__ ypair, int e_fixed, int nw, int nbcnt, size_t wstride)
{
  const int x = blockIdx.x;
  const int wti = x % nw, mb = x / nw;
  int e, nb;
  if (e_fixed >= 0) { e = e_fixed; nb = wti; }
  else { e = wti / nbcnt; nb = wti % nbcnt; }
  const int count = cnt[e];
  if (mb * 128 >= count) return;
  const int off = offs[e];
  const int rows = min(128, count - mb * 128);
  const int c0 = nb * 128;

  __shared__ unsigned short As[2][128 * 64];
  __shared__ unsigned short Bd[2][128 * 64];

  const int t = threadIdx.x;
  const int w = t >> 6, l = t & 63;
  const int sr = l >> 3;
  const int sc = ((l & 7) ^ sr) * 8;
  const size_t wb = (e_fixed >= 0) ? 0 : (size_t)e * wstride;
  const unsigned short* wdE = wdt + wb;

  const unsigned short* aP[4];
  const unsigned short* bP[4];
  int ldsB[4];
#pragma unroll
  for (int i = 0; i < 4; ++i) {
    int rr = w * 32 + i * 8 + sr;
    aP[i] = act + (size_t)(off + mb * 128 + rr) * DFF + sc;
    bP[i] = wdE + (size_t)(c0 + rr) * DFF + sc;
    ldsB[i] = (w * 32 + i * 8) * 64;
  }

  const int fr = l & 15, fq = l >> 4;
  const int wr = (w >> 1) * 64, wc = (w & 1) * 64;
  const int f3 = fr & 7;

  f32x4 acc[4][4];
#pragma unroll
  for (int i = 0; i < 4; ++i)
#pragma unroll
    for (int j = 0; j < 4; ++j) acc[i][j] = (f32x4){0.f, 0.f, 0.f, 0.f};

  auto stage = [&](int b, int kt) {
#pragma unroll
    for (int i = 0; i < 4; ++i) {
      gl2lds16(aP[i] + kt, &As[b][ldsB[i]]);
      gl2lds16(bP[i] + kt, &Bd[b][ldsB[i]]);
    }
  };
  auto compute = [&](int b) {
    short8 af[4][2], bd[4][2];
#pragma unroll
    for (int kk = 0; kk < 2; ++kk) {
      const int ch = ((kk * 4 + fq) ^ f3) * 8;
#pragma unroll
      for (int mi = 0; mi < 4; ++mi)
        af[mi][kk] = *(const short8*)&As[b][(wr + mi * 16 + fr) * 64 + ch];
#pragma unroll
      for (int ni = 0; ni < 4; ++ni)
        bd[ni][kk] = *(const short8*)&Bd[b][(wc + ni * 16 + fr) * 64 + ch];
    }
    __builtin_amdgcn_s_setprio(1);
#pragma unroll
    for (int kk = 0; kk < 2; ++kk)
#pragma unroll
      for (int mi = 0; mi < 4; ++mi)
#pragma unroll
        for (int ni = 0; ni < 4; ++ni)
          acc[mi][ni] = MFMA16(af[mi][kk], bd[ni][kk], acc[mi][ni]);
    __builtin_amdgcn_s_setprio(0);
  };

  const int NK = DFF / 64;     // 22
  stage(0, 0);
  int cur = 0;
  for (int k = 0; k + 1 < NK; ++k) {
    stage(cur ^ 1, (k + 1) * 64);
    asm volatile("s_waitcnt vmcnt(8)" ::: "memory");
    asm volatile("s_barrier" ::: "memory");
    compute(cur);
    asm volatile("s_barrier" ::: "memory");
    cur ^= 1;
  }
  asm volatile("s_waitcnt vmcnt(0)" ::: "memory");
  asm volatile("s_barrier" ::: "memory");
  compute(cur);

#pragma unroll
  for (int mi = 0; mi < 4; ++mi)
#pragma unroll
    for (int ni = 0; ni < 4; ++ni)
#pragma unroll
      for (int j = 0; j < 4; ++j) {
        int r = wr + mi * 16 + fq * 4 + j;
        if (r < rows)
          ypair[(size_t)(off + mb * 128 + r) * HID + (c0 + wc + ni * 16 + fr)] = acc[mi][ni][j];
      }
}

// ---------------- K8: weighted combine ----------------
__global__ __launch_bounds__(256) void combine_k(
    const float* __restrict__ ypair, const int* __restrict__ tok_slot,
    const float* __restrict__ topk_w, float* __restrict__ out)
{
  int i = blockIdx.x * 256 + threadIdx.x;
  int n = i >> 9;
  int dv = (i & 511) * 4;
  int s0 = tok_slot[n * 2], s1 = tok_slot[n * 2 + 1];
  float w0 = topk_w[n * 2], w1 = topk_w[n * 2 + 1];
  float4 a = *(const float4*)&ypair[(size_t)s0 * HID + dv];
  float4 b = *(const float4*)&ypair[(size_t)s1 * HID + dv];
  float4 o;
  o.x = w0 * a.x + w1 * b.x; o.y = w0 * a.y + w1 * b.y;
  o.z = w0 * a.z + w1 * b.z; o.w = w0 * a.w + w1 * b.w;
  *(float4*)&out[(size_t)n * HID + dv] = o;
}

extern "C" void kernel_launch(void* const* d_in, const int* in_sizes, int n_in,
                              void* d_out, int out_size, void* d_ws, size_t ws_size,
                              hipStream_t stream) {
  const float* h  = (const float*)d_in[0];
  const float* gw = (const float*)d_in[1];
  const float* wg = (const float*)d_in[2];
  const float* wu = (const float*)d_in[3];
  const float* wd = (const float*)d_in[4];
  float* out = (float*)d_out;

  const size_t SL = (size_t)DFF * HID;
  char* ws = (char*)d_ws;
  int*   cnt        = (int*)(ws + 0);
  int*   offs       = (int*)(ws + 32);
  int*   cursor     = (int*)(ws + 64);
  int*   pair_token = (int*)(ws + 256);
  float* pair_w     = (float*)(ws + 16640);
  int*   tok_slot   = (int*)(ws + 33024);
  int*   topk_idx   = (int*)(ws + 49408);
  float* topk_w     = (float*)(ws + 65792);
  unsigned short* act = (unsigned short*)(ws + 82176);                // 11,534,336
  unsigned short* hbf = (unsigned short*)(ws + 11616512);             //  8,388,608
  unsigned short* wgt = (unsigned short*)(ws + 20005120);             // 46,137,344 (also wd^T)
  unsigned short* wut = (unsigned short*)(ws + 66142464);             // 46,137,344
  float* ypair_full   = (float*)(ws + 66142464);                      // aliases wut (down phase)
  const size_t NEED_FULL = 112279808ull;

  hipMemsetAsync(ws, 0, 256, stream);

  gate_topk_k<<<N_TOK / 4, 256, 0, stream>>>(h, gw, cnt, topk_idx, topk_w);
  prefix_k<<<1, 64, 0, stream>>>(cnt, offs, cursor);
  scatter_k<<<N_TOK / 256, 256, 0, stream>>>(topk_idx, topk_w, cursor, pair_token, pair_w, tok_slot);
  convert_h_k<<<(N_TOK * HID / 8) / 256, 256, 0, stream>>>(h, hbf);

  if (ws_size >= NEED_FULL) {
    transpose_k<<<dim3(HID / 64, DFF / 64, 16), 256, 0, stream>>>(wg, wgt, wu, wut, HID, DFF, 8);
    gateup8_k<<<176 * 16, 256, 0, stream>>>(hbf, wgt, wut, cnt, offs, pair_token, act,
                                            -1, 176, 22, SL);
    transpose_k<<<dim3(DFF / 64, HID / 64, 8), 256, 0, stream>>>(wd, wgt, wd, wgt, DFF, HID, 8);
    down8_k<<<128 * 16, 256, 0, stream>>>(act, wgt, cnt, offs, ypair_full,
                                          -1, 128, 16, SL);
    combine_k<<<(N_TOK * HID / 4) / 256, 256, 0, stream>>>(ypair_full, tok_slot, topk_w, out);
  } else {
    unsigned short* wgtE = (unsigned short*)(ws + 20005120);
    unsigned short* wutE = (unsigned short*)(ws + 25772288);
    float* ypair = (float*)(ws + 31539456);
    for (int e = 0; e < NEXP; ++e) {
      transpose_k<<<dim3(HID / 64, DFF / 64, 2), 256, 0, stream>>>(wg + e * SL, wgtE, wu + e * SL, wutE, HID, DFF, 1);
      gateup8_k<<<22 * 16, 256, 0, stream>>>(hbf, wgtE, wutE, cnt, offs, pair_token, act,
                                             e, 22, 22, 0);
    }
    for (int e = 0; e < NEXP; ++e) {
      transpose_k<<<dim3(DFF / 64, HID / 64, 1), 256, 0, stream>>>(wd + e * SL, wgtE, wd + e * SL, wgtE, DFF, HID, 1);
      down8_k<<<16 * 16, 256, 0, stream>>>(act, wgtE, cnt, offs, ypair, e, 16, 16, 0);
    }
    combine_k<<<(N_TOK * HID / 4) / 256, 256, 0, stream>>>(ypair, tok_slot, topk_w, out);
  }
}

// Round 9
// 319.902 us; speedup vs baseline: 1.1059x; 1.0177x over previous
//
#include <hip/hip_runtime.h>
#include <hip/hip_bf16.h>
#include <stdint.h>

#define N_TOK 2048
#define HID   2048
#define NEXP  8
#define DFF   1408

typedef __attribute__((ext_vector_type(8))) short short8;
typedef __attribute__((ext_vector_type(4))) float f32x4;

__device__ __forceinline__ unsigned short f2bf(float f) {
  union { float ff; uint32_t u; } v; v.ff = f;
  return (unsigned short)((v.u + 0x7FFFu + ((v.u >> 16) & 1u)) >> 16);
}

__device__ __forceinline__ void gl2lds16(const void* g, void* l) {
  __builtin_amdgcn_global_load_lds(
      (const __attribute__((address_space(1))) void*)g,
      (__attribute__((address_space(3))) void*)l, 16, 0, 0);
}

#define MFMA16(a, b, c) __builtin_amdgcn_mfma_f32_16x16x32_bf16((a), (b), (c), 0, 0, 0)

// ---------------- K1: gating ----------------
__global__ __launch_bounds__(256) void gate_topk_k(
    const float* __restrict__ h, const float* __restrict__ gw,
    int* __restrict__ cnt, int* __restrict__ topk_idx, float* __restrict__ topk_w)
{
  int token = blockIdx.x * 4 + (threadIdx.x >> 6);
  int lane  = threadIdx.x & 63;
  const float* hr = h + (size_t)token * HID;
  float acc[NEXP];
#pragma unroll
  for (int e = 0; e < NEXP; ++e) acc[e] = 0.f;
  for (int i = lane; i < HID; i += 64) {
    float hv = hr[i];
#pragma unroll
    for (int e = 0; e < NEXP; ++e) acc[e] = fmaf(hv, gw[e * HID + i], acc[e]);
  }
#pragma unroll
  for (int e = 0; e < NEXP; ++e) {
    float a = acc[e];
#pragma unroll
    for (int s = 32; s > 0; s >>= 1) a += __shfl_xor(a, s, 64);
    acc[e] = a;
  }
  if (lane == 0) {
    float m = acc[0];
#pragma unroll
    for (int e = 1; e < NEXP; ++e) m = fmaxf(m, acc[e]);
    float w[NEXP]; float s = 0.f;
#pragma unroll
    for (int e = 0; e < NEXP; ++e) { w[e] = __expf(acc[e] - m); s += w[e]; }
    float inv = 1.f / s;
    int i0 = 0; float b0 = acc[0];
#pragma unroll
    for (int e = 1; e < NEXP; ++e) if (acc[e] > b0) { b0 = acc[e]; i0 = e; }
    int i1 = -1; float b1 = -3.4e38f;
#pragma unroll
    for (int e = 0; e < NEXP; ++e) if (e != i0 && acc[e] > b1) { b1 = acc[e]; i1 = e; }
    topk_idx[token * 2 + 0] = i0;
    topk_idx[token * 2 + 1] = i1;
    topk_w[token * 2 + 0] = w[i0] * inv;
    topk_w[token * 2 + 1] = w[i1] * inv;
    atomicAdd(&cnt[i0], 1);
    atomicAdd(&cnt[i1], 1);
  }
}

// ---------------- K2: prefix ----------------
__global__ void prefix_k(const int* __restrict__ cnt, int* __restrict__ offs,
                         int* __restrict__ cursor) {
  if (threadIdx.x == 0 && blockIdx.x == 0) {
    int s = 0;
    for (int e = 0; e < NEXP; ++e) { offs[e] = s; cursor[e] = s; s += cnt[e]; }
  }
}

// ---------------- K3: scatter (+ inverse map tok_slot) ----------------
__global__ __launch_bounds__(256) void scatter_k(
    const int* __restrict__ topk_idx, const float* __restrict__ topk_w,
    int* __restrict__ cursor, int* __restrict__ pair_token, float* __restrict__ pair_w,
    int* __restrict__ tok_slot)
{
  int n = blockIdx.x * 256 + threadIdx.x;
  if (n >= N_TOK) return;
#pragma unroll
  for (int k = 0; k < 2; ++k) {
    int e = topk_idx[n * 2 + k];
    int p = atomicAdd(&cursor[e], 1);
    pair_token[p] = n;
    pair_w[p] = topk_w[n * 2 + k];
    tok_slot[n * 2 + k] = p;
  }
}

// ---------------- K4: h fp32 -> bf16 ----------------
__global__ __launch_bounds__(256) void convert_h_k(const float* __restrict__ src,
                                                   unsigned short* __restrict__ dst) {
  int i = blockIdx.x * 256 + threadIdx.x;
  float4 a = ((const float4*)src)[(size_t)i * 2];
  float4 b = ((const float4*)src)[(size_t)i * 2 + 1];
  unsigned short o[8] = {f2bf(a.x), f2bf(a.y), f2bf(a.z), f2bf(a.w),
                         f2bf(b.x), f2bf(b.y), f2bf(b.z), f2bf(b.w)};
  *(short8*)&dst[(size_t)i * 8] = *(const short8*)o;
}

// ---------------- K5: transpose-convert fp32 [z][R][C] -> bf16 [z][C][R] ----------------
__global__ __launch_bounds__(256) void transpose_k(const float* __restrict__ s1,
                                                   unsigned short* __restrict__ d1,
                                                   const float* __restrict__ s2,
                                                   unsigned short* __restrict__ d2,
                                                   int R, int C, int nz1)
{
  __shared__ unsigned short T[64 * 66];
  const size_t sl = (size_t)R * C;
  int z = blockIdx.z;
  const float* s; unsigned short* d;
  if (z < nz1) { s = s1 + (size_t)z * sl; d = d1 + (size_t)z * sl; }
  else { s = s2 + (size_t)(z - nz1) * sl; d = d2 + (size_t)(z - nz1) * sl; }
  const int rb = blockIdx.x * 64, cb = blockIdx.y * 64;
  const int t = threadIdx.x;
  const int tr = t >> 4, tc = (t & 15) * 4;
  const float* sp = s + (size_t)(rb + tr) * C + cb + tc;
#pragma unroll
  for (int i = 0; i < 4; ++i) {
    float4 v = *(const float4*)(sp + (size_t)i * 16 * C);
    int r = tr + i * 16;
    uint32_t p0 = (uint32_t)f2bf(v.x) | ((uint32_t)f2bf(v.y) << 16);
    uint32_t p1 = (uint32_t)f2bf(v.z) | ((uint32_t)f2bf(v.w) << 16);
    *(uint32_t*)&T[r * 66 + tc]     = p0;
    *(uint32_t*)&T[r * 66 + tc + 2] = p1;
  }
  __syncthreads();
  const int f = t >> 2, ch = (t & 3) * 16;
  unsigned short* dp = d + (size_t)(cb + f) * R + rb + ch;
#pragma unroll
  for (int g = 0; g < 2; ++g) {
    unsigned short buf[8];
#pragma unroll
    for (int j = 0; j < 8; ++j) buf[j] = T[(ch + g * 8 + j) * 66 + f];
    *(short8*)(dp + g * 8) = *(const short8*)buf;
  }
}

// ---------------- K6: grouped GEMM gate+up (64rows x 64f dual, 4 waves, 48KB) -----
// M64 tiles double the active block count (1408) -> 3 blocks/CU residency; the
// inter-block overlap (m114) hides the stage/vmcnt/barrier drain.
__global__ __launch_bounds__(256) void gateup9_k(
    const unsigned short* __restrict__ hbf,
    const unsigned short* __restrict__ wgt, const unsigned short* __restrict__ wut,
    const int* __restrict__ cnt, const int* __restrict__ offs,
    const int* __restrict__ pair_token, unsigned short* __restrict__ act,
    int e_fixed, int nw, int nbcnt, size_t wstride)
{
  const int x = blockIdx.x;
  const int wti = x % nw, mb = x / nw;
  int e, nb;
  if (e_fixed >= 0) { e = e_fixed; nb = wti; }
  else { e = wti / nbcnt; nb = wti % nbcnt; }
  const int count = cnt[e];
  if (mb * 64 >= count) return;
  const int off = offs[e];
  const int rows = min(64, count - mb * 64);
  const int c0 = nb * 64;

  __shared__ unsigned short As[2][64 * 64];
  __shared__ unsigned short Bg[2][64 * 64];
  __shared__ unsigned short Bu[2][64 * 64];
  __shared__ int tok[64];

  const int t = threadIdx.x;
  if (t < 64) tok[t] = pair_token[off + mb * 64 + min(t, rows - 1)];
  __syncthreads();

  const int w = t >> 6, l = t & 63;
  const int sr = l >> 3;
  const int sc = ((l & 7) ^ sr) * 8;
  const int r0 = w * 16 + sr, r1 = w * 16 + 8 + sr;

  const size_t wb = (e_fixed >= 0) ? 0 : (size_t)e * wstride;
  const unsigned short* wgE = wgt + wb;
  const unsigned short* wuE = wut + wb;
  const unsigned short* aP0 = hbf + (size_t)tok[r0] * HID + sc;
  const unsigned short* aP1 = hbf + (size_t)tok[r1] * HID + sc;
  const unsigned short* gP0 = wgE + (size_t)(c0 + r0) * HID + sc;
  const unsigned short* gP1 = wgE + (size_t)(c0 + r1) * HID + sc;
  const unsigned short* uP0 = wuE + (size_t)(c0 + r0) * HID + sc;
  const unsigned short* uP1 = wuE + (size_t)(c0 + r1) * HID + sc;
  const int ldsLo = (w * 16) * 64, ldsHi = (w * 16 + 8) * 64;

  const int fr = l & 15, fq = l >> 4;
  const int wr = (w >> 1) * 32, wc = (w & 1) * 32;
  const int f3 = fr & 7;

  f32x4 accg[2][2], accu[2][2];
#pragma unroll
  for (int i = 0; i < 2; ++i)
#pragma unroll
    for (int j = 0; j < 2; ++j) {
      accg[i][j] = (f32x4){0.f, 0.f, 0.f, 0.f};
      accu[i][j] = (f32x4){0.f, 0.f, 0.f, 0.f};
    }

  auto stage = [&](int b, int kt) {
    gl2lds16(aP0 + kt, &As[b][ldsLo]); gl2lds16(aP1 + kt, &As[b][ldsHi]);
    gl2lds16(gP0 + kt, &Bg[b][ldsLo]); gl2lds16(gP1 + kt, &Bg[b][ldsHi]);
    gl2lds16(uP0 + kt, &Bu[b][ldsLo]); gl2lds16(uP1 + kt, &Bu[b][ldsHi]);
  };
  auto compute = [&](int b) {
    short8 af[2][2], bg[2][2], bu[2][2];
#pragma unroll
    for (int kk = 0; kk < 2; ++kk) {
      const int ch = ((kk * 4 + fq) ^ f3) * 8;
#pragma unroll
      for (int mi = 0; mi < 2; ++mi)
        af[mi][kk] = *(const short8*)&As[b][(wr + mi * 16 + fr) * 64 + ch];
#pragma unroll
      for (int ni = 0; ni < 2; ++ni) {
        bg[ni][kk] = *(const short8*)&Bg[b][(wc + ni * 16 + fr) * 64 + ch];
        bu[ni][kk] = *(const short8*)&Bu[b][(wc + ni * 16 + fr) * 64 + ch];
      }
    }
    __builtin_amdgcn_s_setprio(1);
#pragma unroll
    for (int kk = 0; kk < 2; ++kk)
#pragma unroll
      for (int mi = 0; mi < 2; ++mi)
#pragma unroll
        for (int ni = 0; ni < 2; ++ni) {
          accg[mi][ni] = MFMA16(af[mi][kk], bg[ni][kk], accg[mi][ni]);
          accu[mi][ni] = MFMA16(af[mi][kk], bu[ni][kk], accu[mi][ni]);
        }
    __builtin_amdgcn_s_setprio(0);
  };

  const int NK = HID / 64;     // 32
  stage(0, 0);
  int cur = 0;
  for (int k = 0; k + 1 < NK; ++k) {
    stage(cur ^ 1, (k + 1) * 64);
    asm volatile("s_waitcnt vmcnt(6)" ::: "memory");   // prev tile's 6 loads done
    asm volatile("s_barrier" ::: "memory");
    compute(cur);
    asm volatile("s_barrier" ::: "memory");            // WAR before overwrite
    cur ^= 1;
  }
  asm volatile("s_waitcnt vmcnt(0)" ::: "memory");
  asm volatile("s_barrier" ::: "memory");
  compute(cur);

#pragma unroll
  for (int mi = 0; mi < 2; ++mi)
#pragma unroll
    for (int ni = 0; ni < 2; ++ni)
#pragma unroll
      for (int j = 0; j < 4; ++j) {
        int r = wr + mi * 16 + fq * 4 + j;
        if (r < rows) {
          float g = accg[mi][ni][j], u = accu[mi][ni][j];
          float a = (g / (1.f + __expf(-g))) * u;
          act[(size_t)(off + mb * 64 + r) * DFF + (c0 + wc + ni * 16 + fr)] = f2bf(a);
        }
      }
}

// ---------------- K7: grouped GEMM down (64 x 128, 4 waves, 48KB) -> ypair --------
__global__ __launch_bounds__(256) void down9_k(
    const unsigned short* __restrict__ act, const unsigned short* __restrict__ wdt,
    const int* __restrict__ cnt, const int* __restrict__ offs,
    float* __restrict__ ypair, int e_fixed, int nw, int nbcnt, size_t wstride)
{
  const int x = blockIdx.x;
  const int wti = x % nw, mb = x / nw;
  int e, nb;
  if (e_fixed >= 0) { e = e_fixed; nb = wti; }
  else { e = wti / nbcnt; nb = wti % nbcnt; }
  const int count = cnt[e];
  if (mb * 64 >= count) return;
  const int off = offs[e];
  const int rows = min(64, count - mb * 64);
  const int c0 = nb * 128;

  __shared__ unsigned short As[2][64 * 64];
  __shared__ unsigned short Bd[2][128 * 64];

  const int t = threadIdx.x;
  const int w = t >> 6, l = t & 63;
  const int sr = l >> 3;
  const int sc = ((l & 7) ^ sr) * 8;
  const size_t wb = (e_fixed >= 0) ? 0 : (size_t)e * wstride;
  const unsigned short* wdE = wdt + wb;

  // A: 2 chunks/wave (rows w*16+sr, +8), clamped to valid rows
  const int ra0 = min(w * 16 + sr, rows - 1), ra1 = min(w * 16 + 8 + sr, rows - 1);
  const unsigned short* aP0 = act + (size_t)(off + mb * 64 + ra0) * DFF + sc;
  const unsigned short* aP1 = act + (size_t)(off + mb * 64 + ra1) * DFF + sc;
  const int ldsALo = (w * 16) * 64, ldsAHi = (w * 16 + 8) * 64;
  // B: 4 chunks/wave (rows w*32+i*8+sr)
  const unsigned short* bP[4];
  int ldsB[4];
#pragma unroll
  for (int i = 0; i < 4; ++i) {
    int rr = w * 32 + i * 8 + sr;
    bP[i] = wdE + (size_t)(c0 + rr) * DFF + sc;
    ldsB[i] = (w * 32 + i * 8) * 64;
  }

  const int fr = l & 15, fq = l >> 4;
  const int wr = (w >> 1) * 32, wc = (w & 1) * 64;
  const int f3 = fr & 7;

  f32x4 acc[2][4];
#pragma unroll
  for (int i = 0; i < 2; ++i)
#pragma unroll
    for (int j = 0; j < 4; ++j) acc[i][j] = (f32x4){0.f, 0.f, 0.f, 0.f};

  auto stage = [&](int b, int kt) {
    gl2lds16(aP0 + kt, &As[b][ldsALo]);
    gl2lds16(aP1 + kt, &As[b][ldsAHi]);
#pragma unroll
    for (int i = 0; i < 4; ++i) gl2lds16(bP[i] + kt, &Bd[b][ldsB[i]]);
  };
  auto compute = [&](int b) {
    short8 af[2][2], bd[4][2];
#pragma unroll
    for (int kk = 0; kk < 2; ++kk) {
      const int ch = ((kk * 4 + fq) ^ f3) * 8;
#pragma unroll
      for (int mi = 0; mi < 2; ++mi)
        af[mi][kk] = *(const short8*)&As[b][(wr + mi * 16 + fr) * 64 + ch];
#pragma unroll
      for (int ni = 0; ni < 4; ++ni)
        bd[ni][kk] = *(const short8*)&Bd[b][(wc + ni * 16 + fr) * 64 + ch];
    }
    __builtin_amdgcn_s_setprio(1);
#pragma unroll
    for (int kk = 0; kk < 2; ++kk)
#pragma unroll
      for (int mi = 0; mi < 2; ++mi)
#pragma unroll
        for (int ni = 0; ni < 4; ++ni)
          acc[mi][ni] = MFMA16(af[mi][kk], bd[ni][kk], acc[mi][ni]);
    __builtin_amdgcn_s_setprio(0);
  };

  const int NK = DFF / 64;     // 22
  stage(0, 0);
  int cur = 0;
  for (int k = 0; k + 1 < NK; ++k) {
    stage(cur ^ 1, (k + 1) * 64);
    asm volatile("s_waitcnt vmcnt(6)" ::: "memory");
    asm volatile("s_barrier" ::: "memory");
    compute(cur);
    asm volatile("s_barrier" ::: "memory");
    cur ^= 1;
  }
  asm volatile("s_waitcnt vmcnt(0)" ::: "memory");
  asm volatile("s_barrier" ::: "memory");
  compute(cur);

#pragma unroll
  for (int mi = 0; mi < 2; ++mi)
#pragma unroll
    for (int ni = 0; ni < 4; ++ni)
#pragma unroll
      for (int j = 0; j < 4; ++j) {
        int r = wr + mi * 16 + fq * 4 + j;
        if (r < rows)
          ypair[(size_t)(off + mb * 64 + r) * HID + (c0 + wc + ni * 16 + fr)] = acc[mi][ni][j];
      }
}

// ---------------- K8: weighted combine ----------------
__global__ __launch_bounds__(256) void combine_k(
    const float* __restrict__ ypair, const int* __restrict__ tok_slot,
    const float* __restrict__ topk_w, float* __restrict__ out)
{
  int i = blockIdx.x * 256 + threadIdx.x;
  int n = i >> 9;
  int dv = (i & 511) * 4;
  int s0 = tok_slot[n * 2], s1 = tok_slot[n * 2 + 1];
  float w0 = topk_w[n * 2], w1 = topk_w[n * 2 + 1];
  float4 a = *(const float4*)&ypair[(size_t)s0 * HID + dv];
  float4 b = *(const float4*)&ypair[(size_t)s1 * HID + dv];
  float4 o;
  o.x = w0 * a.x + w1 * b.x; o.y = w0 * a.y + w1 * b.y;
  o.z = w0 * a.z + w1 * b.z; o.w = w0 * a.w + w1 * b.w;
  *(float4*)&out[(size_t)n * HID + dv] = o;
}

extern "C" void kernel_launch(void* const* d_in, const int* in_sizes, int n_in,
                              void* d_out, int out_size, void* d_ws, size_t ws_size,
                              hipStream_t stream) {
  const float* h  = (const float*)d_in[0];
  const float* gw = (const float*)d_in[1];
  const float* wg = (const float*)d_in[2];
  const float* wu = (const float*)d_in[3];
  const float* wd = (const float*)d_in[4];
  float* out = (float*)d_out;

  const size_t SL = (size_t)DFF * HID;
  char* ws = (char*)d_ws;
  int*   cnt        = (int*)(ws + 0);
  int*   offs       = (int*)(ws + 32);
  int*   cursor     = (int*)(ws + 64);
  int*   pair_token = (int*)(ws + 256);
  float* pair_w     = (float*)(ws + 16640);
  int*   tok_slot   = (int*)(ws + 33024);
  int*   topk_idx   = (int*)(ws + 49408);
  float* topk_w     = (float*)(ws + 65792);
  unsigned short* act = (unsigned short*)(ws + 82176);                // 11,534,336
  unsigned short* hbf = (unsigned short*)(ws + 11616512);             //  8,388,608
  unsigned short* wgt = (unsigned short*)(ws + 20005120);             // 46,137,344 (also wd^T)
  unsigned short* wut = (unsigned short*)(ws + 66142464);             // 46,137,344
  float* ypair_full   = (float*)(ws + 66142464);                      // aliases wut (down phase)
  const size_t NEED_FULL = 112279808ull;

  hipMemsetAsync(ws, 0, 256, stream);

  gate_topk_k<<<N_TOK / 4, 256, 0, stream>>>(h, gw, cnt, topk_idx, topk_w);
  prefix_k<<<1, 64, 0, stream>>>(cnt, offs, cursor);
  scatter_k<<<N_TOK / 256, 256, 0, stream>>>(topk_idx, topk_w, cursor, pair_token, pair_w, tok_slot);
  convert_h_k<<<(N_TOK * HID / 8) / 256, 256, 0, stream>>>(h, hbf);

  if (ws_size >= NEED_FULL) {
    transpose_k<<<dim3(HID / 64, DFF / 64, 16), 256, 0, stream>>>(wg, wgt, wu, wut, HID, DFF, 8);
    gateup9_k<<<176 * 16, 256, 0, stream>>>(hbf, wgt, wut, cnt, offs, pair_token, act,
                                            -1, 176, 22, SL);
    transpose_k<<<dim3(DFF / 64, HID / 64, 8), 256, 0, stream>>>(wd, wgt, wd, wgt, DFF, HID, 8);
    down9_k<<<128 * 16, 256, 0, stream>>>(act, wgt, cnt, offs, ypair_full,
                                          -1, 128, 16, SL);
    combine_k<<<(N_TOK * HID / 4) / 256, 256, 0, stream>>>(ypair_full, tok_slot, topk_w, out);
  } else {
    unsigned short* wgtE = (unsigned short*)(ws + 20005120);
    unsigned short* wutE = (unsigned short*)(ws + 25772288);
    float* ypair = (float*)(ws + 31539456);
    for (int e = 0; e < NEXP; ++e) {
      transpose_k<<<dim3(HID / 64, DFF / 64, 2), 256, 0, stream>>>(wg + e * SL, wgtE, wu + e * SL, wutE, HID, DFF, 1);
      gateup9_k<<<22 * 16, 256, 0, stream>>>(hbf, wgtE, wutE, cnt, offs, pair_token, act,
                                             e, 22, 22, 0);
    }
    for (int e = 0; e < NEXP; ++e) {
      transpose_k<<<dim3(DFF / 64, HID / 64, 1), 256, 0, stream>>>(wd + e * SL, wgtE, wd + e * SL, wgtE, DFF, HID, 1);
      down9_k<<<16 * 16, 256, 0, stream>>>(act, wgtE, cnt, offs, ypair, e, 16, 16, 0);
    }
    combine_k<<<(N_TOK * HID / 4) / 256, 256, 0, stream>>>(ypair, tok_slot, topk_w, out);
  }
}